// Round 7
// baseline (19630.350 us; speedup 1.0000x reference)
//
#include <hip/hip_runtime.h>
#include <math.h>

// Problem constants
#define NB    1024      // batch rows == scan steps
#define SEQ   600
#define EDIM  300
#define HDIM  256
#define DIN   903       // 3*E + 3
#define GDIM  1024      // 4*H

#define SENT  0xFFFFFFFFu

// ---------------------------------------------------------------------------
// fast transcendentals: v_exp_f32 / v_rcp_f32 (≤2 ulp, verified absmax 0.0)
// ---------------------------------------------------------------------------
__device__ __forceinline__ float fsig(float x) {
    return __builtin_amdgcn_rcpf(1.f + __builtin_amdgcn_exp2f(x * -1.44269504f));
}
__device__ __forceinline__ float ftanh(float x) {
    return 1.f - 2.f * __builtin_amdgcn_rcpf(1.f + __builtin_amdgcn_exp2f(x * 2.88539008f));
}

// 16-lane rotation-reduce on the VALU pipe (no LDS traffic).
__device__ __forceinline__ float row16_sum(float x) {
    x += __int_as_float(__builtin_amdgcn_update_dpp(0, __float_as_int(x), 0x128, 0xf, 0xf, true));
    x += __int_as_float(__builtin_amdgcn_update_dpp(0, __float_as_int(x), 0x124, 0xf, 0xf, true));
    x += __int_as_float(__builtin_amdgcn_update_dpp(0, __float_as_int(x), 0x122, 0xf, 0xf, true));
    x += __int_as_float(__builtin_amdgcn_update_dpp(0, __float_as_int(x), 0x121, 0xf, 0xf, true));
    return x;
}

// Barrier that waits only LDS ops (lgkmcnt), NOT in-flight global stores.
__device__ __forceinline__ void lds_barrier() {
    asm volatile("s_waitcnt lgkmcnt(0)" ::: "memory");
    __builtin_amdgcn_s_barrier();
}

// agent-scope (via LLC) poll/store — round-3 proven protocol, used ONLY on
// the pipelined (constant-lag) paths ys1->X-stage and X-stage->L2.
__device__ __forceinline__ float poll_agent(const float* p) {
    const unsigned* up = (const unsigned*)p;
    unsigned u; int gd = 0;
    do { u = __hip_atomic_load(up, __ATOMIC_RELAXED, __HIP_MEMORY_SCOPE_AGENT); }
    while (u == SENT && ++gd < (1 << 22));
    return __uint_as_float(u);
}
__device__ __forceinline__ void st_agent(float* p, float v) {
    __hip_atomic_store(p, v, __ATOMIC_RELAXED, __HIP_MEMORY_SCOPE_AGENT);
}

// ---------------------------------------------------------------------------
// Kernel 1: conv (unchanged)
// ---------------------------------------------------------------------------
__global__ __launch_bounds__(256) void conv_kernel(const int* __restrict__ x,
                                                   const float* __restrict__ emb,
                                                   float* __restrict__ X) {
    const int row = blockIdx.x;
    const int tid = threadIdx.x;
    const int* xr = x + (size_t)row * SEQ;

    __shared__ float seg[3][EDIM];
    __shared__ float scnt[3];
    __shared__ float reds[6];
    __shared__ float coss[3];

    if (tid < 6) reds[tid] = 0.f;
    if (tid < 3) scnt[tid] = 0.f;
    __syncthreads();

    {
        int c0 = 0, c1 = 0, c2 = 0;
        for (int t = tid; t < 200; t += 256) {
            c0 += (xr[t]       != 0);
            c1 += (xr[200 + t] != 0);
            c2 += (xr[400 + t] != 0);
        }
        float f0 = (float)c0, f1 = (float)c1, f2 = (float)c2;
        #pragma unroll
        for (int m = 1; m < 64; m <<= 1) {
            f0 += __shfl_xor(f0, m);
            f1 += __shfl_xor(f1, m);
            f2 += __shfl_xor(f2, m);
        }
        if ((tid & 63) == 0) {
            atomicAdd(&scnt[0], f0);
            atomicAdd(&scnt[1], f1);
            atomicAdd(&scnt[2], f2);
        }
    }
    __syncthreads();

    const float inv0 = 1.f / scnt[0], inv1 = 1.f / scnt[1], inv2 = 1.f / scnt[2];

    for (int d = tid; d < EDIM; d += 256) {
        float a0 = 0.f, a1 = 0.f, a2 = 0.f;
        for (int t = 0; t < 200; t++) {
            a0 += emb[(size_t)xr[t]       * EDIM + d];
            a1 += emb[(size_t)xr[200 + t] * EDIM + d];
            a2 += emb[(size_t)xr[400 + t] * EDIM + d];
        }
        seg[0][d] = a0 * inv0;
        seg[1][d] = a1 * inv1;
        seg[2][d] = a2 * inv2;
    }
    __syncthreads();

    {
        float p0 = 0, p1 = 0, p2 = 0, p3 = 0, p4 = 0, p5 = 0;
        for (int d = tid; d < EDIM; d += 256) {
            float a = seg[0][d], b = seg[1][d], c = seg[2][d];
            p0 += a * a; p1 += b * b; p2 += c * c;
            p3 += a * b; p4 += b * c; p5 += a * c;
        }
        #pragma unroll
        for (int m = 1; m < 64; m <<= 1) {
            p0 += __shfl_xor(p0, m); p1 += __shfl_xor(p1, m);
            p2 += __shfl_xor(p2, m); p3 += __shfl_xor(p3, m);
            p4 += __shfl_xor(p4, m); p5 += __shfl_xor(p5, m);
        }
        if ((tid & 63) == 0) {
            atomicAdd(&reds[0], p0); atomicAdd(&reds[1], p1);
            atomicAdd(&reds[2], p2); atomicAdd(&reds[3], p3);
            atomicAdd(&reds[4], p4); atomicAdd(&reds[5], p5);
        }
    }
    __syncthreads();
    if (tid == 0) {
        float nt = fmaxf(sqrtf(reds[0]), 1e-8f);
        float nu = fmaxf(sqrtf(reds[1]), 1e-8f);
        float nj = fmaxf(sqrtf(reds[2]), 1e-8f);
        coss[0] = reds[3] / (nt * nu);
        coss[1] = reds[4] / (nu * nj);
        coss[2] = reds[5] / (nt * nj);
    }
    __syncthreads();

    float* Xr = X + (size_t)row * DIN;
    for (int col = tid; col < DIN; col += 256) {
        float v;
        if      (col < 300)  v = seg[0][col];
        else if (col == 300) v = coss[0];
        else if (col < 601)  v = seg[1][col - 301];
        else if (col == 601) v = coss[1];
        else if (col < 902)  v = seg[2][col - 602];
        else                 v = coss[2];
        Xr[col] = v;
    }
}

// ---------------------------------------------------------------------------
// Kernel 2: GEMM (unchanged) — G1 = X @ Wih0^T + b_ih0 + b_hh0
// ---------------------------------------------------------------------------
__global__ __launch_bounds__(256) void gemm_bias(const float* __restrict__ A,
                                                 const float* __restrict__ Bm,
                                                 const float* __restrict__ bias1,
                                                 const float* __restrict__ bias2,
                                                 float* __restrict__ C, int K) {
    __shared__ float As[16][68];
    __shared__ float Bs[16][68];
    const int tid = threadIdx.x;
    const int tx = tid & 15, ty = tid >> 4;
    const int m0 = blockIdx.y * 64, n0 = blockIdx.x * 64;

    float acc[4][4] = {};
    for (int k0 = 0; k0 < K; k0 += 16) {
        #pragma unroll
        for (int i = 0; i < 4; i++) {
            int e  = tid + i * 256;
            int rr = e >> 4, kk = e & 15;
            int k  = k0 + kk;
            As[kk][rr] = (k < K) ? A[(size_t)(m0 + rr) * K + k] : 0.f;
            Bs[kk][rr] = (k < K) ? Bm[(size_t)(n0 + rr) * K + k] : 0.f;
        }
        __syncthreads();
        #pragma unroll
        for (int kk = 0; kk < 16; kk++) {
            float a[4], b[4];
            #pragma unroll
            for (int i = 0; i < 4; i++) { a[i] = As[kk][ty * 4 + i]; b[i] = Bs[kk][tx * 4 + i]; }
            #pragma unroll
            for (int i = 0; i < 4; i++)
                #pragma unroll
                for (int j = 0; j < 4; j++)
                    acc[i][j] += a[i] * b[j];
        }
        __syncthreads();
    }
    #pragma unroll
    for (int i = 0; i < 4; i++) {
        int m = m0 + ty * 4 + i;
        #pragma unroll
        for (int j = 0; j < 4; j++) {
            int n = n0 + tx * 4 + j;
            C[(size_t)m * GDIM + n] = acc[i][j] + bias1[n] + bias2[n];
        }
    }
}

// ---------------------------------------------------------------------------
// Kernel 3: fused 2-layer LSTM — ONE WG PER LAYER, LDS-only recurrence.
// Grid: 6 WGs x 1024 threads.
//   bid 0 = L1 recurrence, bid 1 = L2 recurrence (whole layer in one CU:
//     h-exchange via LDS + 2 intra-WG barriers; NO global transport on the
//     serial loop).
//   bid 2..5 = X-stage n: P2[t] = Wih1·ys1[t] + biases for elems [n*64,+64)
//     (pipelined behind L1 via agent mailboxes — constant lag, off the
//     critical path; round-3 verified structure).
// Recurrence mapping: thread (qq = tid>>8, e = tid&255) computes the
// qq-th 64-col partial of gate rows {g*256+e}. Weights: 256 VGPRs/thread
// (whole Whh in the CU register file). Per wave, all lanes share one
// 64-float h-slice -> 16 ds_read_b128 broadcasts (conflict-free).
// Partials -> praw[16][256] (conflict-free) -> 256 epilogue threads reduce,
// add G-terms (L1: G1 prefetched; L2: P2 prefetched from mailP with re-poll),
// nonlinearity, write hb[next]. Two lgkm-only barriers per step.
// ---------------------------------------------------------------------------
__global__ __launch_bounds__(1024) void lstm_fused(
    const float* __restrict__ G1,
    const float* __restrict__ Whh0,
    const float* __restrict__ Wih1,
    const float* __restrict__ Whh1,
    const float* __restrict__ b_ih1,
    const float* __restrict__ b_hh1,
    const float* __restrict__ h0,
    const float* __restrict__ c0,
    float* mailX, float* mailP,
    float* ys2, float* out)
{
    const int tid = threadIdx.x;
    const int bid = blockIdx.x;

    __shared__ __align__(16) float hb[2][HDIM];     // h, double-buffered
    __shared__ float praw[16][HDIM];                // partials [g*4+qq][e]
    __shared__ __align__(16) float xl[2][16][20];   // X-stage h broadcast

    if (bid < 2) {
        // ================== recurrence: one WG = one layer ==================
        const int L  = bid;
        const int e  = tid & 255;
        const int qq = tid >> 8;
        const float* Wh = L ? Whh1 : Whh0;

        // weights: rows g*256+e, cols qq*64..+63  (256 VGPRs)
        float4 w[4][16];
        #pragma unroll
        for (int g = 0; g < 4; g++)
            #pragma unroll
            for (int j = 0; j < 16; j++)
                w[g][j] = *(const float4*)&Wh[(size_t)(g * 256 + e) * HDIM + qq * 64 + j * 4];

        float c = 0.f;
        if (tid < HDIM) {
            c = c0[L * HDIM + tid];
            hb[0][tid] = h0[L * HDIM + tid];
        }
        __syncthreads();

        for (int t = 0; t < NB; t++) {
            const int nb = t & 1;

            // ---- prefetch G-terms (epilogue threads), hides under matvec ----
            float    g1r[4];
            unsigned p2r[4];
            const unsigned* pp = nullptr;
            if (tid < HDIM) {
                if (L == 0) {
                    #pragma unroll
                    for (int g = 0; g < 4; g++)
                        g1r[g] = G1[(size_t)t * GDIM + g * 256 + tid];
                } else {
                    pp = (const unsigned*)(mailP + ((size_t)(tid >> 6) * NB + t) * HDIM)
                         + (tid & 63);
                    #pragma unroll
                    for (int g = 0; g < 4; g++)
                        p2r[g] = __hip_atomic_load(pp + g * 64, __ATOMIC_RELAXED,
                                                   __HIP_MEMORY_SCOPE_AGENT);
                }
            }

            // ---- matvec: 4 gate rows x 64 cols; h via broadcast b128 ----
            const float4* h4 = (const float4*)&hb[nb][qq * 64];
            float a0 = 0.f, a1 = 0.f, a2 = 0.f, a3 = 0.f;
            #pragma unroll
            for (int j = 0; j < 16; j++) {
                float4 hv = h4[j];
                float4 w0 = w[0][j], w1 = w[1][j], w2 = w[2][j], w3 = w[3][j];
                a0 += hv.x * w0.x + hv.y * w0.y + hv.z * w0.z + hv.w * w0.w;
                a1 += hv.x * w1.x + hv.y * w1.y + hv.z * w1.z + hv.w * w1.w;
                a2 += hv.x * w2.x + hv.y * w2.y + hv.z * w2.z + hv.w * w2.w;
                a3 += hv.x * w3.x + hv.y * w3.y + hv.z * w3.z + hv.w * w3.w;
            }
            praw[     qq][e] = a0;
            praw[ 4 + qq][e] = a1;
            praw[ 8 + qq][e] = a2;
            praw[12 + qq][e] = a3;
            lds_barrier();                       // partials complete

            // ---- epilogue: reduce + gates + state + publish ----
            if (tid < HDIM) {
                float s0 = praw[0][tid] + praw[1][tid] + praw[2][tid] + praw[3][tid];
                float s1 = praw[4][tid] + praw[5][tid] + praw[6][tid] + praw[7][tid];
                float s2 = praw[8][tid] + praw[9][tid] + praw[10][tid] + praw[11][tid];
                float s3 = praw[12][tid] + praw[13][tid] + praw[14][tid] + praw[15][tid];
                if (L == 0) {
                    s0 += g1r[0]; s1 += g1r[1]; s2 += g1r[2]; s3 += g1r[3];
                } else {
                    #pragma unroll
                    for (int g = 0; g < 4; g++) {
                        int gd = 0;
                        while (p2r[g] == SENT && ++gd < (1 << 22))
                            p2r[g] = __hip_atomic_load(pp + g * 64, __ATOMIC_RELAXED,
                                                       __HIP_MEMORY_SCOPE_AGENT);
                    }
                    s0 += __uint_as_float(p2r[0]); s1 += __uint_as_float(p2r[1]);
                    s2 += __uint_as_float(p2r[2]); s3 += __uint_as_float(p2r[3]);
                }
                float ig = fsig(s0), fg = fsig(s1), og = fsig(s3);
                c = fg * c + ig * ftanh(s2);
                float h = og * ftanh(c);
                hb[nb ^ 1][tid] = h;
                if (L == 0) {
                    #pragma unroll
                    for (int r = 0; r < 4; r++)
                        st_agent(mailX + ((size_t)r * NB + t) * HDIM + tid, h);
                } else {
                    ys2[(size_t)t * HDIM + tid] = h;
                }
                if (t == NB - 1) {
                    out[1024 + L * HDIM + tid] = h;    // hn
                    out[1536 + L * HDIM + tid] = c;    // cn
                }
            }
            lds_barrier();                       // hb[next] complete
        }
    } else {
        // ================== X-stage: P2[t] = Wih1·ys1[t] + biases ===========
        const int n = bid - 2;                   // 0..3, elems [n*64, +64)
        const int l = tid & 63;
        const int v = tid >> 6;                  // wave 0..15
        const int k = l >> 4;
        const int q = l & 15;
        const int e = n * 64 + 4 * v + k;
        const float* xsrc = mailX + (size_t)n * NB * HDIM;   // private replica

        float4 wi[4][4];
        #pragma unroll
        for (int g = 0; g < 4; g++)
            #pragma unroll
            for (int j = 0; j < 4; j++)
                wi[g][j] = *(const float4*)&Wih1[(size_t)(g * 256 + e) * HDIM + q * 16 + j * 4];

        float bsum = 0.f;
        if (q < 4) bsum = b_ih1[q * 256 + e] + b_hh1[q * 256 + e];

        for (int t = 0; t < NB; t++) {
            const int nb = t & 1;
            if (tid < HDIM)
                xl[nb][tid >> 4][tid & 15] = poll_agent(xsrc + (size_t)t * HDIM + tid);
            lds_barrier();

            float a0 = 0.f, a1 = 0.f, a2 = 0.f, a3 = 0.f;
            #pragma unroll
            for (int j = 0; j < 4; j++) {
                float4 hv = *(const float4*)&xl[nb][q][j * 4];
                float4 w0 = wi[0][j], w1 = wi[1][j], w2 = wi[2][j], w3 = wi[3][j];
                a0 += hv.x * w0.x + hv.y * w0.y + hv.z * w0.z + hv.w * w0.w;
                a1 += hv.x * w1.x + hv.y * w1.y + hv.z * w1.z + hv.w * w1.w;
                a2 += hv.x * w2.x + hv.y * w2.y + hv.z * w2.z + hv.w * w2.w;
                a3 += hv.x * w3.x + hv.y * w3.y + hv.z * w3.z + hv.w * w3.w;
            }
            a0 = row16_sum(a0); a1 = row16_sum(a1);
            a2 = row16_sum(a2); a3 = row16_sum(a3);

            if (q < 4) {
                float pv = (q == 0 ? a0 : q == 1 ? a1 : q == 2 ? a2 : a3) + bsum;
                st_agent(mailP + ((size_t)n * NB + t) * HDIM + q * 64 + (4 * v + k), pv);
            }
        }
    }
}

// ---------------------------------------------------------------------------
// Kernel 4: fc head (unchanged)
// ---------------------------------------------------------------------------
__global__ __launch_bounds__(256) void fc_kernel(const float* __restrict__ ys2,
                                                 const float* __restrict__ fc_w,
                                                 const float* __restrict__ fc_b,
                                                 float* __restrict__ out) {
    const int row  = blockIdx.x * 4 + (threadIdx.x >> 6);
    const int lane = threadIdx.x & 63;
    float4 y = ((const float4*)(ys2 + (size_t)row * HDIM))[lane];
    float4 wv = ((const float4*)fc_w)[lane];
    float d = y.x * wv.x + y.y * wv.y + y.z * wv.z + y.w * wv.w;
    #pragma unroll
    for (int m = 1; m < 64; m <<= 1) d += __shfl_xor(d, m);
    if (lane == 0) out[row] = 1.f / (1.f + expf(-(d + fc_b[0])));
}

// ---------------------------------------------------------------------------
extern "C" void kernel_launch(void* const* d_in, const int* in_sizes, int n_in,
                              void* d_out, int out_size, void* d_ws, size_t ws_size,
                              hipStream_t stream) {
    const int*   x     = (const int*)  d_in[0];
    const float* h0    = (const float*)d_in[1];
    const float* c0    = (const float*)d_in[2];
    const float* emb   = (const float*)d_in[3];
    const float* w_ih0 = (const float*)d_in[4];
    const float* w_hh0 = (const float*)d_in[5];
    const float* b_ih0 = (const float*)d_in[6];
    const float* b_hh0 = (const float*)d_in[7];
    const float* w_ih1 = (const float*)d_in[8];
    const float* w_hh1 = (const float*)d_in[9];
    const float* b_ih1 = (const float*)d_in[10];
    const float* b_hh1 = (const float*)d_in[11];
    const float* fc_w  = (const float*)d_in[12];
    const float* fc_b  = (const float*)d_in[13];
    float* out = (float*)d_out;

    // workspace layout (floats), ~17 MB — no aliasing.
    float* mailX = (float*)d_ws;                       // 4*NB*HDIM  (4 MB)
    float* mailP = mailX + (size_t)4 * NB * HDIM;      // 4*NB*HDIM  (4 MB)
    float* G1    = mailP + (size_t)4 * NB * HDIM;      // NB*GDIM    (4 MB)
    float* ys2   = G1    + (size_t)NB * GDIM;          // NB*HDIM    (1 MB)
    float* X     = ys2   + (size_t)NB * HDIM;          // NB*DIN     (3.7 MB)

    // sentinel-fill mailX + mailP (0xFFFFFFFF = NaN, never produced): 8 MB
    hipMemsetAsync(mailX, 0xFF, (size_t)8 * NB * HDIM * sizeof(float), stream);

    conv_kernel<<<NB, 256, 0, stream>>>(x, emb, X);

    gemm_bias<<<dim3(16, 16), 256, 0, stream>>>(X, w_ih0, b_ih0, b_hh0, G1, DIN);

    lstm_fused<<<6, 1024, 0, stream>>>(G1, w_hh0, w_ih1, w_hh1, b_ih1, b_hh1,
                                       h0, c0, mailX, mailP, ys2, out);

    fc_kernel<<<NB / 4, 256, 0, stream>>>(ys2, fc_w, fc_b, out);
}